// Round 11
// baseline (284.354 us; speedup 1.0000x reference)
//
#include <hip/hip_runtime.h>
#include <hip/hip_bf16.h>

// GCN: h = (0.5A)^2 x ; h = relu(h W1 + b1) ; h = (0.5A)^2 h ; h = h W2 + b2
// r23: r22 with the NT-builtin compile fix. __builtin_nontemporal_store
//  rejects HIP_vector_type (float4/uint4 are classes); cast through clang
//  ext_vector_type typedefs (f32x4 / u32x4) instead — same dwordx4 stores
//  with the nt bit.
//  Mechanism (r22): each spmm streams cv (6.4MB, read-once) and STORES its
//  output (6.4-25.6MB, write-allocate) while randomly gathering a 6.4-12.8MB
//  table that barely exceeds the 4MB/XCD L2. Output lines allocated in
//  producer XCD L2 are useless to the next kernel but evict the CURRENT
//  kernel's gather table. NT stores for spmm outputs + NT loads for cv keep
//  L2 for the table; L3 is memory-side so NT data still lands in Infinity
//  Cache for the next stage.
//  Everything else byte-identical to r21 (279.7us, passed).
// Kernels: K1 convert+hist+wfrag, K2m scan+base, K3 coarse scatter,
//          K4 phase sort, S1, S2f, S3, S4.  (8 total)
// Buffers (d_out used as raw scratch until final write):
//  xb  = d_out[0,6.4MB)   t0b = d_out[6.4,12.8MB)   t2b = d_out[12.8,25.6MB)
//  ws: t3b[0,12.8MB) (stgk/stgv overlay, dead by K4 end) | row_ptr N+1 |
//      region_off NREG+1 | partial G*256 | bases G*256 | W1f 4KB | W2f 8KB |
//      cv E*4B

#define REGION_SHIFT 9               // 512 rows per region
#define REGION_SIZE  (1 << REGION_SHIFT)
#define COL_MASK 0x1FFFF             // 17 bits, N=100000 < 131072
#define GBUILD 256                   // blocks for K1/K3 (chunking must match!)
#define NPH_SHIFT 3                  // 8 column phases (col>>14: 0..6 used)
#define NKEY (REGION_SIZE << NPH_SHIFT)  // 4096 sort keys

typedef unsigned short u16;
typedef unsigned int   u32;
typedef __attribute__((ext_vector_type(8))) short bf16x8;
typedef __attribute__((ext_vector_type(4))) float f32x4;
typedef __attribute__((ext_vector_type(4))) unsigned int u32x4;

__device__ inline float bflo(u32 w) { return __uint_as_float(w << 16); }
__device__ inline float bfhi(u32 w) { return __uint_as_float(w & 0xffff0000u); }
// pack two fp32 -> bf16 pair (RTN-even), a in low half
__device__ inline u32 bfpack(float a, float b) {
    u32 ua = __float_as_uint(a), ub = __float_as_uint(b);
    ua = (ua + 0x7fffu + ((ua >> 16) & 1u)) >> 16;
    ub = (ub + 0x7fffu + ((ub >> 16) & 1u)) & 0xffff0000u;
    return ua | ub;
}
__device__ inline u16 bf1(float f) {
    u32 u = __float_as_uint(f);
    return (u16)((u + 0x7fffu + ((u >> 16) & 1u)) >> 16);
}

// ---- K1: fp32->bf16 convert + per-block LDS region hist + weight frags ----
__global__ void region_count_kernel(const int* __restrict__ er, int E,
                                    int* __restrict__ partial,
                                    const float* __restrict__ x,
                                    u16* __restrict__ xb, int n4,
                                    const float* __restrict__ W1,
                                    const float* __restrict__ W2,
                                    u16* __restrict__ W1f,
                                    u16* __restrict__ W2f) {
    for (int i = blockIdx.x * 256 + threadIdx.x; i < n4; i += gridDim.x * 256) {
        float4 a = reinterpret_cast<const float4*>(x)[i];
        uint2 o;
        o.x = bfpack(a.x, a.y);
        o.y = bfpack(a.z, a.w);
        reinterpret_cast<uint2*>(xb)[i] = o;
    }
    if (blockIdx.x == 0) {
        // W1f[t][quad][n16][j] = bf16(W1[(quad*8+j)*64 + t*16 + n16])
        for (int idx = threadIdx.x; idx < 2048; idx += 256) {
            int j = idx & 7, n16 = (idx >> 3) & 15;
            int quad = (idx >> 7) & 3, t = (idx >> 9) & 3;
            W1f[idx] = bf1(W1[(quad * 8 + j) * 64 + t * 16 + n16]);
        }
        // W2f[t][half][quad][n16][j] = bf16(W2[(half*32+quad*8+j)*64 + t*16 + n16])
        for (int idx = threadIdx.x; idx < 4096; idx += 256) {
            int j = idx & 7, n16 = (idx >> 3) & 15;
            int quad = (idx >> 7) & 3, half = (idx >> 9) & 1, t = (idx >> 10) & 3;
            W2f[idx] = bf1(W2[(half * 32 + quad * 8 + j) * 64 + t * 16 + n16]);
        }
    }
    __shared__ int hist[256];
    int t = threadIdx.x;
    hist[t] = 0;
    __syncthreads();
    int chunk = (E + gridDim.x - 1) / gridDim.x;
    int s = blockIdx.x * chunk;
    int e = min(E, s + chunk);
    for (int i = s + t; i < e; i += 256)
        atomicAdd(&hist[er[i] >> REGION_SHIFT], 1);
    __syncthreads();
    partial[blockIdx.x * 256 + t] = hist[t];   // single-writer 1KB row
}

// ---- K2m: merged scan+base. Block r: region_off[r] from partial (read-only)
//      + per-block scatter bases for region r -> bases[] (separate array). --
__global__ void region_scanbase_kernel(const int* __restrict__ partial,
                                       int* __restrict__ bases,
                                       int* __restrict__ region_off,
                                       int nreg, int E, int G) {
    __shared__ int s[256];
    int r = blockIdx.x;
    if (r >= nreg) return;
    int t = threadIdx.x;
    // region_off[r] = sum over blocks b, regions q<r of partial[b*256+q]
    int rowsum = 0;
    const int* prow = partial + t * 256;       // thread t = block t's row
    for (int q = 0; q < r; q++) rowsum += prow[q];   // contiguous slice
    s[t] = rowsum;
    __syncthreads();
    for (int off = 128; off > 0; off >>= 1) {
        if (t < off) s[t] += s[t + off];
        __syncthreads();
    }
    int off_r = s[0];
    __syncthreads();
    if (t == 0) {
        region_off[r] = off_r;
        if (r == 0) region_off[nreg] = E;
    }
    // per-block exclusive scan of partial[t*256+r] over t -> bases
    int c = prow[r];
    s[t] = c;
    __syncthreads();
    for (int off = 1; off < 256; off <<= 1) {
        int xv = (t >= off) ? s[t - off] : 0;
        __syncthreads();
        s[t] += xv;
        __syncthreads();
    }
    bases[t * 256 + r] = off_r + s[t] - c;     // exclusive base
}

// ---- K3: coarse scatter, LDS rank only (no global atomics) ----
// stgk: col | localrow<<17 ; stgv: bf16 bits of 0.5*val (15 bits, >=0)
__global__ void coarse_scatter_kernel(const int* __restrict__ er,
                                      const int* __restrict__ ec,
                                      const float* __restrict__ ev, int E,
                                      const int* __restrict__ bases,
                                      u32* __restrict__ stgk,
                                      u16* __restrict__ stgv) {
    __shared__ int cnt2[256], gbase[256];
    int t = threadIdx.x;
    cnt2[t] = 0;
    gbase[t] = bases[blockIdx.x * 256 + t];
    __syncthreads();
    int chunk = (E + gridDim.x - 1) / gridDim.x;   // identical to K1
    int s0 = blockIdx.x * chunk;
    int e0 = min(E, s0 + chunk);
    for (int i = s0 + t; i < e0; i += 256) {
        int r = er[i];
        int b = r >> REGION_SHIFT;
        int rank = atomicAdd(&cnt2[b], 1);
        int p = gbase[b] + rank;                   // block-private run
        stgk[p] = (u32)ec[i] | ((u32)(r & (REGION_SIZE - 1)) << 17);
        stgv[p] = bf1(0.5f * ev[i]);               // positive: 15 bits
    }
}

// ---- K4: per-region LDS counting sort by (localrow, col-phase) ------------
// key = lrow<<3 | (col>>14). Row r's edges = keys [r*8,(r+1)*8) contiguous,
// phase-ordered -> row_ptr[row] = prefix at key r*8. hist doubles as wp.
__global__ void region_sort_kernel(const u32* __restrict__ stgk,
                                   const u16* __restrict__ stgv,
                                   const int* __restrict__ region_off,
                                   int* __restrict__ row_ptr,
                                   u32* __restrict__ cv, int N, int E) {
    __shared__ int hist[NKEY];      // counts -> exclusive prefix -> wp
    __shared__ int psum[256];
    int cb = blockIdx.x;
    int lo = cb << REGION_SHIFT;
    if (lo >= N) return;
    int hi = min(lo + REGION_SIZE, N);
    int cnt = hi - lo;
    int t = threadIdx.x;
    for (int k = t; k < NKEY; k += 256) hist[k] = 0;
    __syncthreads();
    int start = region_off[cb];
    int end   = region_off[cb + 1];
    for (int q = start + t; q < end; q += 256) {
        u32 key = stgk[q];
        int lr = key >> 17;
        int ph = (int)((key & COL_MASK) >> 14);    // 0..6
        atomicAdd(&hist[(lr << NPH_SHIFT) | ph], 1);
    }
    __syncthreads();
    // block-wide exclusive scan of hist[0..NKEY): 16 keys/thread
    int base_t = t * 16;
    int vals[16];
    int local = 0;
#pragma unroll
    for (int k = 0; k < 16; k++) { vals[k] = hist[base_t + k]; local += vals[k]; }
    psum[t] = local;
    __syncthreads();
    for (int off = 1; off < 256; off <<= 1) {
        int xv = (t >= off) ? psum[t - off] : 0;
        __syncthreads();
        psum[t] += xv;
        __syncthreads();
    }
    int run = start + psum[t] - local;             // global exclusive offset
#pragma unroll
    for (int k = 0; k < 16; k++) { hist[base_t + k] = run; run += vals[k]; }
    __syncthreads();
    // row_ptr from prefixes (before scatter destroys them)
    for (int r = t; r < cnt; r += 256)
        row_ptr[lo + r] = hist[r << NPH_SHIFT];
    if (cb == 0 && t == 0) row_ptr[N] = E;
    __syncthreads();
    // scatter (hist now serves as running write pointers)
    for (int q = start + t; q < end; q += 256) {
        u32 key = stgk[q];
        u32 val = stgv[q];
        int lr = key >> 17;
        int ph = (int)((key & COL_MASK) >> 14);
        int p = atomicAdd(&hist[(lr << NPH_SHIFT) | ph], 1);   // LDS atomic
        cv[p] = (val << 17) | (key & COL_MASK);
    }
}

// ---------------- CSR SpMM, gather-side, bf16 table / fp32 accum ------------
__device__ inline void fma8(float acc[8], float v, uint4 w) {
    acc[0] = fmaf(v, bflo(w.x), acc[0]); acc[1] = fmaf(v, bfhi(w.x), acc[1]);
    acc[2] = fmaf(v, bflo(w.y), acc[2]); acc[3] = fmaf(v, bfhi(w.y), acc[3]);
    acc[4] = fmaf(v, bflo(w.z), acc[4]); acc[5] = fmaf(v, bfhi(w.z), acc[5]);
    acc[6] = fmaf(v, bflo(w.w), acc[6]); acc[7] = fmaf(v, bfhi(w.w), acc[7]);
}
__device__ inline float cvval(u32 q) { return __uint_as_float((q >> 17) << 16); }

// Shared spmm inner loop: 8 gathers in flight (MLP), then 4-wide, scalar tail.
// cv loads are NON-TEMPORAL (read-once stream; keep L2 for the gather table).
template <int D>
__device__ inline void spmm_row(const u16* __restrict__ h,
                                const u32* __restrict__ cv,
                                int start, int end, int sub, float acc[8]) {
    int j = start;
    for (; j + 8 <= end; j += 8) {
        u32 q0 = __builtin_nontemporal_load(cv + j);
        u32 q1 = __builtin_nontemporal_load(cv + j + 1);
        u32 q2 = __builtin_nontemporal_load(cv + j + 2);
        u32 q3 = __builtin_nontemporal_load(cv + j + 3);
        u32 q4 = __builtin_nontemporal_load(cv + j + 4);
        u32 q5 = __builtin_nontemporal_load(cv + j + 5);
        u32 q6 = __builtin_nontemporal_load(cv + j + 6);
        u32 q7 = __builtin_nontemporal_load(cv + j + 7);
        uint4 w0 = reinterpret_cast<const uint4*>(h + (size_t)(q0 & COL_MASK) * D)[sub];
        uint4 w1 = reinterpret_cast<const uint4*>(h + (size_t)(q1 & COL_MASK) * D)[sub];
        uint4 w2 = reinterpret_cast<const uint4*>(h + (size_t)(q2 & COL_MASK) * D)[sub];
        uint4 w3 = reinterpret_cast<const uint4*>(h + (size_t)(q3 & COL_MASK) * D)[sub];
        uint4 w4 = reinterpret_cast<const uint4*>(h + (size_t)(q4 & COL_MASK) * D)[sub];
        uint4 w5 = reinterpret_cast<const uint4*>(h + (size_t)(q5 & COL_MASK) * D)[sub];
        uint4 w6 = reinterpret_cast<const uint4*>(h + (size_t)(q6 & COL_MASK) * D)[sub];
        uint4 w7 = reinterpret_cast<const uint4*>(h + (size_t)(q7 & COL_MASK) * D)[sub];
        fma8(acc, cvval(q0), w0);
        fma8(acc, cvval(q1), w1);
        fma8(acc, cvval(q2), w2);
        fma8(acc, cvval(q3), w3);
        fma8(acc, cvval(q4), w4);
        fma8(acc, cvval(q5), w5);
        fma8(acc, cvval(q6), w6);
        fma8(acc, cvval(q7), w7);
    }
    for (; j + 4 <= end; j += 4) {
        u32 q0 = __builtin_nontemporal_load(cv + j);
        u32 q1 = __builtin_nontemporal_load(cv + j + 1);
        u32 q2 = __builtin_nontemporal_load(cv + j + 2);
        u32 q3 = __builtin_nontemporal_load(cv + j + 3);
        uint4 w0 = reinterpret_cast<const uint4*>(h + (size_t)(q0 & COL_MASK) * D)[sub];
        uint4 w1 = reinterpret_cast<const uint4*>(h + (size_t)(q1 & COL_MASK) * D)[sub];
        uint4 w2 = reinterpret_cast<const uint4*>(h + (size_t)(q2 & COL_MASK) * D)[sub];
        uint4 w3 = reinterpret_cast<const uint4*>(h + (size_t)(q3 & COL_MASK) * D)[sub];
        fma8(acc, cvval(q0), w0);
        fma8(acc, cvval(q1), w1);
        fma8(acc, cvval(q2), w2);
        fma8(acc, cvval(q3), w3);
    }
    for (; j < end; j++) {
        u32 q = __builtin_nontemporal_load(cv + j);
        uint4 w = reinterpret_cast<const uint4*>(h + (size_t)(q & COL_MASK) * D)[sub];
        fma8(acc, cvval(q), w);
    }
}

// D features/row; 8 features (16B) per lane; LPR = D/8 lanes per row.
// Output stores NON-TEMPORAL (via ext_vector types): write-allocate lines are
// useless cross-kernel but evict this kernel's gather table.
template <int D, bool FINAL>
__global__ __launch_bounds__(256) void spmm_bf16_kernel(
        const u16* __restrict__ h,
        const int* __restrict__ row_ptr,
        const u32* __restrict__ cv,
        void* __restrict__ outp,
        const float* __restrict__ bias,  // used iff FINAL
        int N) {
    constexpr int LPR = D / 8;
    int gid = blockIdx.x * 256 + threadIdx.x;
    int row = gid / LPR;
    int sub = gid % LPR;
    if (row >= N) return;
    int start = row_ptr[row];
    int end   = row_ptr[row + 1];
    float acc[8] = {0.f, 0.f, 0.f, 0.f, 0.f, 0.f, 0.f, 0.f};
    spmm_row<D>(h, cv, start, end, sub, acc);
    if (FINAL) {
        float* op = (float*)outp + (size_t)row * 64 + sub * 8;
#pragma unroll
        for (int k = 0; k < 8; k++) acc[k] += bias[sub * 8 + k];
        f32x4 lo4 = {acc[0], acc[1], acc[2], acc[3]};
        f32x4 hi4 = {acc[4], acc[5], acc[6], acc[7]};
        __builtin_nontemporal_store(lo4, reinterpret_cast<f32x4*>(op));
        __builtin_nontemporal_store(hi4, reinterpret_cast<f32x4*>(op) + 1);
    } else {
        u16* ob = (u16*)outp + (size_t)row * D + sub * 8;
        u32x4 o;
        o.x = bfpack(acc[0], acc[1]);
        o.y = bfpack(acc[2], acc[3]);
        o.z = bfpack(acc[4], acc[5]);
        o.w = bfpack(acc[6], acc[7]);
        __builtin_nontemporal_store(o, reinterpret_cast<u32x4*>(ob));
    }
}

// ---- S2f: spmm32 + dense fused: t2 = relu(spmm(t0)@W1 + b1) @ W2 ----------
// Block = 256 thr = 4 waves; LPR=4 -> 64 rows/block = one 16-row tile/wave.
// spmm acc -> LDS tile (bf16) -> per-wave 16x16x32 MFMA (verified r10 layout).
__global__ __launch_bounds__(256) void spmm_dense_kernel(
        const u16* __restrict__ h,       // t0b [N,32] bf16
        const int* __restrict__ row_ptr,
        const u32* __restrict__ cv,
        const u16* __restrict__ W1f,     // [4][4][16][8] bf16 frags
        const float* __restrict__ b1,    // [64]
        const u16* __restrict__ W2f,     // [4][2][4][16][8] bf16 frags
        u16* __restrict__ outb,          // t2b [N,64] bf16
        int N) {
    __shared__ __align__(16) u16 tiles[4][16][80];   // pad 80 (160B = 16B-mult)
    int tid = threadIdx.x;
    int lane = tid & 63;
    int wave = tid >> 6;
    int tilebase = blockIdx.x * 64 + wave * 16;
    if (tilebase >= N) return;           // wave-uniform (N % 16 == 0)
    int gid = blockIdx.x * 256 + tid;
    int row = gid >> 2;                  // LPR = 4
    int sub = gid & 3;

    // ---- spmm D=32 ----
    bool vr = row < N;
    int start = vr ? row_ptr[row] : 0;
    int end   = vr ? row_ptr[row + 1] : 0;
    float acc[8] = {0.f, 0.f, 0.f, 0.f, 0.f, 0.f, 0.f, 0.f};
    spmm_row<32>(h, cv, start, end, sub, acc);

    // ---- stash t1 tile in LDS as bf16 (per-wave private; in-order DS) ----
    u16 (*tile)[80] = tiles[wave];
    {
        uint4 o;
        o.x = bfpack(acc[0], acc[1]);
        o.y = bfpack(acc[2], acc[3]);
        o.z = bfpack(acc[4], acc[5]);
        o.w = bfpack(acc[6], acc[7]);
        *reinterpret_cast<uint4*>(&tile[lane >> 2][sub * 8]) = o;
    }

    // ---- dense: relu(t1@W1+b1)@W2 on MFMA 16x16x32 (verified r10 layout) --
    int n16 = lane & 15;
    int quad = lane >> 4;
    bf16x8 w1f[4];
    bf16x8 w2f[4][2];
#pragma unroll
    for (int t = 0; t < 4; t++) {
        w1f[t] = *reinterpret_cast<const bf16x8*>(&W1f[((t * 4 + quad) * 16 + n16) * 8]);
        w2f[t][0] = *reinterpret_cast<const bf16x8*>(&W2f[(((t * 2 + 0) * 4 + quad) * 16 + n16) * 8]);
        w2f[t][1] = *reinterpret_cast<const bf16x8*>(&W2f[(((t * 2 + 1) * 4 + quad) * 16 + n16) * 8]);
    }
    float b1v[4];
#pragma unroll
    for (int t = 0; t < 4; t++) b1v[t] = b1[t * 16 + n16];

    bf16x8 a1 = *reinterpret_cast<const bf16x8*>(&tile[n16][quad * 8]);
    f32x4 zero = {0.f, 0.f, 0.f, 0.f};
    f32x4 c[4];
#pragma unroll
    for (int t = 0; t < 4; t++)
        c[t] = __builtin_amdgcn_mfma_f32_16x16x32_bf16(a1, w1f[t], zero, 0, 0, 0);

#pragma unroll
    for (int t = 0; t < 4; t++)
#pragma unroll
        for (int i = 0; i < 4; i++)
            tile[quad * 4 + i][t * 16 + n16] = bf1(fmaxf(c[t][i] + b1v[t], 0.f));

    bf16x8 a2_0 = *reinterpret_cast<const bf16x8*>(&tile[n16][quad * 8]);
    bf16x8 a2_1 = *reinterpret_cast<const bf16x8*>(&tile[n16][32 + quad * 8]);
    f32x4 d[4];
#pragma unroll
    for (int t = 0; t < 4; t++) {
        d[t] = __builtin_amdgcn_mfma_f32_16x16x32_bf16(a2_0, w2f[t][0], zero, 0, 0, 0);
        d[t] = __builtin_amdgcn_mfma_f32_16x16x32_bf16(a2_1, w2f[t][1], d[t], 0, 0, 0);
    }

#pragma unroll
    for (int t = 0; t < 4; t++)
#pragma unroll
        for (int i = 0; i < 4; i++)
            tile[quad * 4 + i][t * 16 + n16] = bf1(d[t][i]);

#pragma unroll
    for (int half = 0; half < 2; half++) {
        int g = half * 512 + lane * 8;
        int r = g >> 6, cc = g & 63;
        int grow = tilebase + r;
        if (grow < N)
            __builtin_nontemporal_store(
                *reinterpret_cast<const u32x4*>(&tile[r][cc]),
                reinterpret_cast<u32x4*>(outb + (size_t)grow * 64 + cc));
    }
}

extern "C" void kernel_launch(void* const* d_in, const int* in_sizes, int n_in,
                              void* d_out, int out_size, void* d_ws, size_t ws_size,
                              hipStream_t stream) {
    const float* x        = (const float*)d_in[0];
    const float* edge_val = (const float*)d_in[1];
    const int*   edge_row = (const int*)d_in[2];
    const int*   edge_col = (const int*)d_in[3];
    const float* W1       = (const float*)d_in[4];
    const float* b1       = (const float*)d_in[5];
    const float* W2       = (const float*)d_in[6];
    const float* b2       = (const float*)d_in[7];
    float* out = (float*)d_out;

    const int N = in_sizes[0] / 32;   // 100000
    const int E = in_sizes[1];        // 1600000
    const int NREG = (N + REGION_SIZE - 1) >> REGION_SHIFT;  // 196

    // --- d_out as raw scratch (fp32 final write overwrites all) ---
    u16* xb  = (u16*)d_out;                    // N*32 bf16
    u16* t0b = xb + (size_t)N * 32;            // N*32 bf16
    u16* t2b = (u16*)d_out + (size_t)N * 64;   // N*64 bf16

    // --- ws layout ---
    u16* t3b  = (u16*)d_ws;                    // N*64 bf16
    u32* stgk = (u32*)d_ws;                    // E u32 overlay (build only)
    u16* stgv = (u16*)((char*)d_ws + (size_t)E * 4);  // E u16 overlay
    int* row_ptr    = (int*)((char*)d_ws + (size_t)N * 64 * 2);  // N+1
    int* region_off = row_ptr + (N + 1);       // NREG+1
    int* partial    = region_off + (NREG + 1); // GBUILD*256
    int* bases      = partial + GBUILD * 256;  // GBUILD*256
    size_t wOff = (((size_t)((char*)(bases + GBUILD * 256) - (char*)d_ws)) + 15) & ~(size_t)15;
    u16* W1f = (u16*)((char*)d_ws + wOff);     // 2048 bf16
    u16* W2f = W1f + 2048;                     // 4096 bf16
    size_t cvOff = (((size_t)((char*)(W2f + 4096) - (char*)d_ws)) + 15) & ~(size_t)15;
    u32* cv = (u32*)((char*)d_ws + cvOff);     // E packed 4B edges

    int n4 = (N * 32) / 4;

    // ---- CSR build (2-pass radix, zero global atomics, no memset) ----
    region_count_kernel<<<GBUILD, 256, 0, stream>>>(edge_row, E, partial, x, xb, n4,
                                                    W1, W2, W1f, W2f);
    region_scanbase_kernel<<<NREG, 256, 0, stream>>>(partial, bases, region_off,
                                                     NREG, E, GBUILD);
    coarse_scatter_kernel<<<GBUILD, 256, 0, stream>>>(edge_row, edge_col, edge_val,
                                                      E, bases, stgk, stgv);
    region_sort_kernel<<<NREG, 256, 0, stream>>>(stgk, stgv, region_off,
                                                 row_ptr, cv, N, E);

    // ---- pipeline ----
    int g32 = (N * 4 + 255) / 256;   // D=32: 4 lanes/row (also 64 rows/block)
    int g64 = (N * 8 + 255) / 256;   // D=64: 8 lanes/row

    spmm_bf16_kernel<32, false><<<g32, 256, 0, stream>>>(xb, row_ptr, cv, t0b, nullptr, N);
    spmm_dense_kernel<<<g32, 256, 0, stream>>>(t0b, row_ptr, cv, W1f, b1, W2f, t2b, N);
    spmm_bf16_kernel<64, false><<<g64, 256, 0, stream>>>(t2b, row_ptr, cv, t3b, nullptr, N);
    spmm_bf16_kernel<64, true><<<g64, 256, 0, stream>>>(t3b, row_ptr, cv, out, b2, N);
}

// Round 12
// 271.366 us; speedup vs baseline: 1.0479x; 1.0479x over previous
//
#include <hip/hip_runtime.h>
#include <hip/hip_bf16.h>

// GCN: h = (0.5A)^2 x ; h = relu(h W1 + b1) ; h = (0.5A)^2 h ; h = h W2 + b2
// r24: FINAL — revert r23's non-temporal hints (null-to-negative: 284.4 vs
//  279.7). Byte-identical to r21, the best verified kernel (279.7us).
//  Closed hypotheses (counter-evidence): divergence (r16, -29us regression),
//  MLP depth (r17, +14us win, saturated at 8), grid-sync build fusion (r18,
//  269us spin disaster), build traffic (r19/r20, -2us), phase locality (r21,
//  null), L2 pollution via NT (r23, null). Remaining time is the L3
//  random-gather floor: ~614MB @ ~3.6TB/s effective ≈ 170us spmm chain
//  + ~40us build + ~25us dispatch boundaries + ~15us streams.
// Kernels: K1 convert+hist+wfrag, K2m scan+base, K3 coarse scatter,
//          K4 phase sort, S1, S2f, S3, S4.  (8 total)
// Buffers (d_out used as raw scratch until final write):
//  xb  = d_out[0,6.4MB)   t0b = d_out[6.4,12.8MB)   t2b = d_out[12.8,25.6MB)
//  ws: t3b[0,12.8MB) (stgk/stgv overlay, dead by K4 end) | row_ptr N+1 |
//      region_off NREG+1 | partial G*256 | bases G*256 | W1f 4KB | W2f 8KB |
//      cv E*4B

#define REGION_SHIFT 9               // 512 rows per region
#define REGION_SIZE  (1 << REGION_SHIFT)
#define COL_MASK 0x1FFFF             // 17 bits, N=100000 < 131072
#define GBUILD 256                   // blocks for K1/K3 (chunking must match!)
#define NPH_SHIFT 3                  // 8 column phases (col>>14: 0..6 used)
#define NKEY (REGION_SIZE << NPH_SHIFT)  // 4096 sort keys

typedef unsigned short u16;
typedef unsigned int   u32;
typedef __attribute__((ext_vector_type(8))) short bf16x8;
typedef __attribute__((ext_vector_type(4))) float f32x4;

__device__ inline float bflo(u32 w) { return __uint_as_float(w << 16); }
__device__ inline float bfhi(u32 w) { return __uint_as_float(w & 0xffff0000u); }
// pack two fp32 -> bf16 pair (RTN-even), a in low half
__device__ inline u32 bfpack(float a, float b) {
    u32 ua = __float_as_uint(a), ub = __float_as_uint(b);
    ua = (ua + 0x7fffu + ((ua >> 16) & 1u)) >> 16;
    ub = (ub + 0x7fffu + ((ub >> 16) & 1u)) & 0xffff0000u;
    return ua | ub;
}
__device__ inline u16 bf1(float f) {
    u32 u = __float_as_uint(f);
    return (u16)((u + 0x7fffu + ((u >> 16) & 1u)) >> 16);
}

// ---- K1: fp32->bf16 convert + per-block LDS region hist + weight frags ----
__global__ void region_count_kernel(const int* __restrict__ er, int E,
                                    int* __restrict__ partial,
                                    const float* __restrict__ x,
                                    u16* __restrict__ xb, int n4,
                                    const float* __restrict__ W1,
                                    const float* __restrict__ W2,
                                    u16* __restrict__ W1f,
                                    u16* __restrict__ W2f) {
    for (int i = blockIdx.x * 256 + threadIdx.x; i < n4; i += gridDim.x * 256) {
        float4 a = reinterpret_cast<const float4*>(x)[i];
        uint2 o;
        o.x = bfpack(a.x, a.y);
        o.y = bfpack(a.z, a.w);
        reinterpret_cast<uint2*>(xb)[i] = o;
    }
    if (blockIdx.x == 0) {
        // W1f[t][quad][n16][j] = bf16(W1[(quad*8+j)*64 + t*16 + n16])
        for (int idx = threadIdx.x; idx < 2048; idx += 256) {
            int j = idx & 7, n16 = (idx >> 3) & 15;
            int quad = (idx >> 7) & 3, t = (idx >> 9) & 3;
            W1f[idx] = bf1(W1[(quad * 8 + j) * 64 + t * 16 + n16]);
        }
        // W2f[t][half][quad][n16][j] = bf16(W2[(half*32+quad*8+j)*64 + t*16 + n16])
        for (int idx = threadIdx.x; idx < 4096; idx += 256) {
            int j = idx & 7, n16 = (idx >> 3) & 15;
            int quad = (idx >> 7) & 3, half = (idx >> 9) & 1, t = (idx >> 10) & 3;
            W2f[idx] = bf1(W2[(half * 32 + quad * 8 + j) * 64 + t * 16 + n16]);
        }
    }
    __shared__ int hist[256];
    int t = threadIdx.x;
    hist[t] = 0;
    __syncthreads();
    int chunk = (E + gridDim.x - 1) / gridDim.x;
    int s = blockIdx.x * chunk;
    int e = min(E, s + chunk);
    for (int i = s + t; i < e; i += 256)
        atomicAdd(&hist[er[i] >> REGION_SHIFT], 1);
    __syncthreads();
    partial[blockIdx.x * 256 + t] = hist[t];   // single-writer 1KB row
}

// ---- K2m: merged scan+base. Block r: region_off[r] from partial (read-only)
//      + per-block scatter bases for region r -> bases[] (separate array). --
__global__ void region_scanbase_kernel(const int* __restrict__ partial,
                                       int* __restrict__ bases,
                                       int* __restrict__ region_off,
                                       int nreg, int E, int G) {
    __shared__ int s[256];
    int r = blockIdx.x;
    if (r >= nreg) return;
    int t = threadIdx.x;
    // region_off[r] = sum over blocks b, regions q<r of partial[b*256+q]
    int rowsum = 0;
    const int* prow = partial + t * 256;       // thread t = block t's row
    for (int q = 0; q < r; q++) rowsum += prow[q];   // contiguous slice
    s[t] = rowsum;
    __syncthreads();
    for (int off = 128; off > 0; off >>= 1) {
        if (t < off) s[t] += s[t + off];
        __syncthreads();
    }
    int off_r = s[0];
    __syncthreads();
    if (t == 0) {
        region_off[r] = off_r;
        if (r == 0) region_off[nreg] = E;
    }
    // per-block exclusive scan of partial[t*256+r] over t -> bases
    int c = prow[r];
    s[t] = c;
    __syncthreads();
    for (int off = 1; off < 256; off <<= 1) {
        int xv = (t >= off) ? s[t - off] : 0;
        __syncthreads();
        s[t] += xv;
        __syncthreads();
    }
    bases[t * 256 + r] = off_r + s[t] - c;     // exclusive base
}

// ---- K3: coarse scatter, LDS rank only (no global atomics) ----
// stgk: col | localrow<<17 ; stgv: bf16 bits of 0.5*val (15 bits, >=0)
__global__ void coarse_scatter_kernel(const int* __restrict__ er,
                                      const int* __restrict__ ec,
                                      const float* __restrict__ ev, int E,
                                      const int* __restrict__ bases,
                                      u32* __restrict__ stgk,
                                      u16* __restrict__ stgv) {
    __shared__ int cnt2[256], gbase[256];
    int t = threadIdx.x;
    cnt2[t] = 0;
    gbase[t] = bases[blockIdx.x * 256 + t];
    __syncthreads();
    int chunk = (E + gridDim.x - 1) / gridDim.x;   // identical to K1
    int s0 = blockIdx.x * chunk;
    int e0 = min(E, s0 + chunk);
    for (int i = s0 + t; i < e0; i += 256) {
        int r = er[i];
        int b = r >> REGION_SHIFT;
        int rank = atomicAdd(&cnt2[b], 1);
        int p = gbase[b] + rank;                   // block-private run
        stgk[p] = (u32)ec[i] | ((u32)(r & (REGION_SIZE - 1)) << 17);
        stgv[p] = bf1(0.5f * ev[i]);               // positive: 15 bits
    }
}

// ---- K4: per-region LDS counting sort by (localrow, col-phase) ------------
// key = lrow<<3 | (col>>14). Row r's edges = keys [r*8,(r+1)*8) contiguous,
// phase-ordered -> row_ptr[row] = prefix at key r*8. hist doubles as wp.
__global__ void region_sort_kernel(const u32* __restrict__ stgk,
                                   const u16* __restrict__ stgv,
                                   const int* __restrict__ region_off,
                                   int* __restrict__ row_ptr,
                                   u32* __restrict__ cv, int N, int E) {
    __shared__ int hist[NKEY];      // counts -> exclusive prefix -> wp
    __shared__ int psum[256];
    int cb = blockIdx.x;
    int lo = cb << REGION_SHIFT;
    if (lo >= N) return;
    int hi = min(lo + REGION_SIZE, N);
    int cnt = hi - lo;
    int t = threadIdx.x;
    for (int k = t; k < NKEY; k += 256) hist[k] = 0;
    __syncthreads();
    int start = region_off[cb];
    int end   = region_off[cb + 1];
    for (int q = start + t; q < end; q += 256) {
        u32 key = stgk[q];
        int lr = key >> 17;
        int ph = (int)((key & COL_MASK) >> 14);    // 0..6
        atomicAdd(&hist[(lr << NPH_SHIFT) | ph], 1);
    }
    __syncthreads();
    // block-wide exclusive scan of hist[0..NKEY): 16 keys/thread
    int base_t = t * 16;
    int vals[16];
    int local = 0;
#pragma unroll
    for (int k = 0; k < 16; k++) { vals[k] = hist[base_t + k]; local += vals[k]; }
    psum[t] = local;
    __syncthreads();
    for (int off = 1; off < 256; off <<= 1) {
        int xv = (t >= off) ? psum[t - off] : 0;
        __syncthreads();
        psum[t] += xv;
        __syncthreads();
    }
    int run = start + psum[t] - local;             // global exclusive offset
#pragma unroll
    for (int k = 0; k < 16; k++) { hist[base_t + k] = run; run += vals[k]; }
    __syncthreads();
    // row_ptr from prefixes (before scatter destroys them)
    for (int r = t; r < cnt; r += 256)
        row_ptr[lo + r] = hist[r << NPH_SHIFT];
    if (cb == 0 && t == 0) row_ptr[N] = E;
    __syncthreads();
    // scatter (hist now serves as running write pointers)
    for (int q = start + t; q < end; q += 256) {
        u32 key = stgk[q];
        u32 val = stgv[q];
        int lr = key >> 17;
        int ph = (int)((key & COL_MASK) >> 14);
        int p = atomicAdd(&hist[(lr << NPH_SHIFT) | ph], 1);   // LDS atomic
        cv[p] = (val << 17) | (key & COL_MASK);
    }
}

// ---------------- CSR SpMM, gather-side, bf16 table / fp32 accum ------------
__device__ inline void fma8(float acc[8], float v, uint4 w) {
    acc[0] = fmaf(v, bflo(w.x), acc[0]); acc[1] = fmaf(v, bfhi(w.x), acc[1]);
    acc[2] = fmaf(v, bflo(w.y), acc[2]); acc[3] = fmaf(v, bfhi(w.y), acc[3]);
    acc[4] = fmaf(v, bflo(w.z), acc[4]); acc[5] = fmaf(v, bfhi(w.z), acc[5]);
    acc[6] = fmaf(v, bflo(w.w), acc[6]); acc[7] = fmaf(v, bfhi(w.w), acc[7]);
}
__device__ inline float cvval(u32 q) { return __uint_as_float((q >> 17) << 16); }

// Shared spmm inner loop: 8 gathers in flight (MLP), then 4-wide, scalar tail.
template <int D>
__device__ inline void spmm_row(const u16* __restrict__ h,
                                const u32* __restrict__ cv,
                                int start, int end, int sub, float acc[8]) {
    int j = start;
    for (; j + 8 <= end; j += 8) {
        u32 q0 = cv[j],     q1 = cv[j + 1], q2 = cv[j + 2], q3 = cv[j + 3];
        u32 q4 = cv[j + 4], q5 = cv[j + 5], q6 = cv[j + 6], q7 = cv[j + 7];
        uint4 w0 = reinterpret_cast<const uint4*>(h + (size_t)(q0 & COL_MASK) * D)[sub];
        uint4 w1 = reinterpret_cast<const uint4*>(h + (size_t)(q1 & COL_MASK) * D)[sub];
        uint4 w2 = reinterpret_cast<const uint4*>(h + (size_t)(q2 & COL_MASK) * D)[sub];
        uint4 w3 = reinterpret_cast<const uint4*>(h + (size_t)(q3 & COL_MASK) * D)[sub];
        uint4 w4 = reinterpret_cast<const uint4*>(h + (size_t)(q4 & COL_MASK) * D)[sub];
        uint4 w5 = reinterpret_cast<const uint4*>(h + (size_t)(q5 & COL_MASK) * D)[sub];
        uint4 w6 = reinterpret_cast<const uint4*>(h + (size_t)(q6 & COL_MASK) * D)[sub];
        uint4 w7 = reinterpret_cast<const uint4*>(h + (size_t)(q7 & COL_MASK) * D)[sub];
        fma8(acc, cvval(q0), w0);
        fma8(acc, cvval(q1), w1);
        fma8(acc, cvval(q2), w2);
        fma8(acc, cvval(q3), w3);
        fma8(acc, cvval(q4), w4);
        fma8(acc, cvval(q5), w5);
        fma8(acc, cvval(q6), w6);
        fma8(acc, cvval(q7), w7);
    }
    for (; j + 4 <= end; j += 4) {
        u32 q0 = cv[j], q1 = cv[j + 1], q2 = cv[j + 2], q3 = cv[j + 3];
        uint4 w0 = reinterpret_cast<const uint4*>(h + (size_t)(q0 & COL_MASK) * D)[sub];
        uint4 w1 = reinterpret_cast<const uint4*>(h + (size_t)(q1 & COL_MASK) * D)[sub];
        uint4 w2 = reinterpret_cast<const uint4*>(h + (size_t)(q2 & COL_MASK) * D)[sub];
        uint4 w3 = reinterpret_cast<const uint4*>(h + (size_t)(q3 & COL_MASK) * D)[sub];
        fma8(acc, cvval(q0), w0);
        fma8(acc, cvval(q1), w1);
        fma8(acc, cvval(q2), w2);
        fma8(acc, cvval(q3), w3);
    }
    for (; j < end; j++) {
        u32 q = cv[j];
        uint4 w = reinterpret_cast<const uint4*>(h + (size_t)(q & COL_MASK) * D)[sub];
        fma8(acc, cvval(q), w);
    }
}

// D features/row; 8 features (16B) per lane; LPR = D/8 lanes per row.
template <int D, bool FINAL>
__global__ __launch_bounds__(256) void spmm_bf16_kernel(
        const u16* __restrict__ h,
        const int* __restrict__ row_ptr,
        const u32* __restrict__ cv,
        void* __restrict__ outp,
        const float* __restrict__ bias,  // used iff FINAL
        int N) {
    constexpr int LPR = D / 8;
    int gid = blockIdx.x * 256 + threadIdx.x;
    int row = gid / LPR;
    int sub = gid % LPR;
    if (row >= N) return;
    int start = row_ptr[row];
    int end   = row_ptr[row + 1];
    float acc[8] = {0.f, 0.f, 0.f, 0.f, 0.f, 0.f, 0.f, 0.f};
    spmm_row<D>(h, cv, start, end, sub, acc);
    if (FINAL) {
        float* op = (float*)outp + (size_t)row * 64 + sub * 8;
#pragma unroll
        for (int k = 0; k < 8; k++) acc[k] += bias[sub * 8 + k];
        reinterpret_cast<float4*>(op)[0] = make_float4(acc[0], acc[1], acc[2], acc[3]);
        reinterpret_cast<float4*>(op)[1] = make_float4(acc[4], acc[5], acc[6], acc[7]);
    } else {
        u16* ob = (u16*)outp + (size_t)row * D + sub * 8;
        uint4 o;
        o.x = bfpack(acc[0], acc[1]);
        o.y = bfpack(acc[2], acc[3]);
        o.z = bfpack(acc[4], acc[5]);
        o.w = bfpack(acc[6], acc[7]);
        reinterpret_cast<uint4*>(ob)[0] = o;
    }
}

// ---- S2f: spmm32 + dense fused: t2 = relu(spmm(t0)@W1 + b1) @ W2 ----------
// Block = 256 thr = 4 waves; LPR=4 -> 64 rows/block = one 16-row tile/wave.
// spmm acc -> LDS tile (bf16) -> per-wave 16x16x32 MFMA (verified r10 layout).
__global__ __launch_bounds__(256) void spmm_dense_kernel(
        const u16* __restrict__ h,       // t0b [N,32] bf16
        const int* __restrict__ row_ptr,
        const u32* __restrict__ cv,
        const u16* __restrict__ W1f,     // [4][4][16][8] bf16 frags
        const float* __restrict__ b1,    // [64]
        const u16* __restrict__ W2f,     // [4][2][4][16][8] bf16 frags
        u16* __restrict__ outb,          // t2b [N,64] bf16
        int N) {
    __shared__ __align__(16) u16 tiles[4][16][80];   // pad 80 (160B = 16B-mult)
    int tid = threadIdx.x;
    int lane = tid & 63;
    int wave = tid >> 6;
    int tilebase = blockIdx.x * 64 + wave * 16;
    if (tilebase >= N) return;           // wave-uniform (N % 16 == 0)
    int gid = blockIdx.x * 256 + tid;
    int row = gid >> 2;                  // LPR = 4
    int sub = gid & 3;

    // ---- spmm D=32 ----
    bool vr = row < N;
    int start = vr ? row_ptr[row] : 0;
    int end   = vr ? row_ptr[row + 1] : 0;
    float acc[8] = {0.f, 0.f, 0.f, 0.f, 0.f, 0.f, 0.f, 0.f};
    spmm_row<32>(h, cv, start, end, sub, acc);

    // ---- stash t1 tile in LDS as bf16 (per-wave private; in-order DS) ----
    u16 (*tile)[80] = tiles[wave];
    {
        uint4 o;
        o.x = bfpack(acc[0], acc[1]);
        o.y = bfpack(acc[2], acc[3]);
        o.z = bfpack(acc[4], acc[5]);
        o.w = bfpack(acc[6], acc[7]);
        *reinterpret_cast<uint4*>(&tile[lane >> 2][sub * 8]) = o;
    }

    // ---- dense: relu(t1@W1+b1)@W2 on MFMA 16x16x32 (verified r10 layout) --
    int n16 = lane & 15;
    int quad = lane >> 4;
    bf16x8 w1f[4];
    bf16x8 w2f[4][2];
#pragma unroll
    for (int t = 0; t < 4; t++) {
        w1f[t] = *reinterpret_cast<const bf16x8*>(&W1f[((t * 4 + quad) * 16 + n16) * 8]);
        w2f[t][0] = *reinterpret_cast<const bf16x8*>(&W2f[(((t * 2 + 0) * 4 + quad) * 16 + n16) * 8]);
        w2f[t][1] = *reinterpret_cast<const bf16x8*>(&W2f[(((t * 2 + 1) * 4 + quad) * 16 + n16) * 8]);
    }
    float b1v[4];
#pragma unroll
    for (int t = 0; t < 4; t++) b1v[t] = b1[t * 16 + n16];

    bf16x8 a1 = *reinterpret_cast<const bf16x8*>(&tile[n16][quad * 8]);
    f32x4 zero = {0.f, 0.f, 0.f, 0.f};
    f32x4 c[4];
#pragma unroll
    for (int t = 0; t < 4; t++)
        c[t] = __builtin_amdgcn_mfma_f32_16x16x32_bf16(a1, w1f[t], zero, 0, 0, 0);

#pragma unroll
    for (int t = 0; t < 4; t++)
#pragma unroll
        for (int i = 0; i < 4; i++)
            tile[quad * 4 + i][t * 16 + n16] = bf1(fmaxf(c[t][i] + b1v[t], 0.f));

    bf16x8 a2_0 = *reinterpret_cast<const bf16x8*>(&tile[n16][quad * 8]);
    bf16x8 a2_1 = *reinterpret_cast<const bf16x8*>(&tile[n16][32 + quad * 8]);
    f32x4 d[4];
#pragma unroll
    for (int t = 0; t < 4; t++) {
        d[t] = __builtin_amdgcn_mfma_f32_16x16x32_bf16(a2_0, w2f[t][0], zero, 0, 0, 0);
        d[t] = __builtin_amdgcn_mfma_f32_16x16x32_bf16(a2_1, w2f[t][1], d[t], 0, 0, 0);
    }

#pragma unroll
    for (int t = 0; t < 4; t++)
#pragma unroll
        for (int i = 0; i < 4; i++)
            tile[quad * 4 + i][t * 16 + n16] = bf1(d[t][i]);

#pragma unroll
    for (int half = 0; half < 2; half++) {
        int g = half * 512 + lane * 8;
        int r = g >> 6, cc = g & 63;
        int grow = tilebase + r;
        if (grow < N)
            *reinterpret_cast<uint4*>(outb + (size_t)grow * 64 + cc) =
                *reinterpret_cast<const uint4*>(&tile[r][cc]);
    }
}

extern "C" void kernel_launch(void* const* d_in, const int* in_sizes, int n_in,
                              void* d_out, int out_size, void* d_ws, size_t ws_size,
                              hipStream_t stream) {
    const float* x        = (const float*)d_in[0];
    const float* edge_val = (const float*)d_in[1];
    const int*   edge_row = (const int*)d_in[2];
    const int*   edge_col = (const int*)d_in[3];
    const float* W1       = (const float*)d_in[4];
    const float* b1       = (const float*)d_in[5];
    const float* W2       = (const float*)d_in[6];
    const float* b2       = (const float*)d_in[7];
    float* out = (float*)d_out;

    const int N = in_sizes[0] / 32;   // 100000
    const int E = in_sizes[1];        // 1600000
    const int NREG = (N + REGION_SIZE - 1) >> REGION_SHIFT;  // 196

    // --- d_out as raw scratch (fp32 final write overwrites all) ---
    u16* xb  = (u16*)d_out;                    // N*32 bf16
    u16* t0b = xb + (size_t)N * 32;            // N*32 bf16
    u16* t2b = (u16*)d_out + (size_t)N * 64;   // N*64 bf16

    // --- ws layout ---
    u16* t3b  = (u16*)d_ws;                    // N*64 bf16
    u32* stgk = (u32*)d_ws;                    // E u32 overlay (build only)
    u16* stgv = (u16*)((char*)d_ws + (size_t)E * 4);  // E u16 overlay
    int* row_ptr    = (int*)((char*)d_ws + (size_t)N * 64 * 2);  // N+1
    int* region_off = row_ptr + (N + 1);       // NREG+1
    int* partial    = region_off + (NREG + 1); // GBUILD*256
    int* bases      = partial + GBUILD * 256;  // GBUILD*256
    size_t wOff = (((size_t)((char*)(bases + GBUILD * 256) - (char*)d_ws)) + 15) & ~(size_t)15;
    u16* W1f = (u16*)((char*)d_ws + wOff);     // 2048 bf16
    u16* W2f = W1f + 2048;                     // 4096 bf16
    size_t cvOff = (((size_t)((char*)(W2f + 4096) - (char*)d_ws)) + 15) & ~(size_t)15;
    u32* cv = (u32*)((char*)d_ws + cvOff);     // E packed 4B edges

    int n4 = (N * 32) / 4;

    // ---- CSR build (2-pass radix, zero global atomics, no memset) ----
    region_count_kernel<<<GBUILD, 256, 0, stream>>>(edge_row, E, partial, x, xb, n4,
                                                    W1, W2, W1f, W2f);
    region_scanbase_kernel<<<NREG, 256, 0, stream>>>(partial, bases, region_off,
                                                     NREG, E, GBUILD);
    coarse_scatter_kernel<<<GBUILD, 256, 0, stream>>>(edge_row, edge_col, edge_val,
                                                      E, bases, stgk, stgv);
    region_sort_kernel<<<NREG, 256, 0, stream>>>(stgk, stgv, region_off,
                                                 row_ptr, cv, N, E);

    // ---- pipeline ----
    int g32 = (N * 4 + 255) / 256;   // D=32: 4 lanes/row (also 64 rows/block)
    int g64 = (N * 8 + 255) / 256;   // D=64: 8 lanes/row

    spmm_bf16_kernel<32, false><<<g32, 256, 0, stream>>>(xb, row_ptr, cv, t0b, nullptr, N);
    spmm_dense_kernel<<<g32, 256, 0, stream>>>(t0b, row_ptr, cv, W1f, b1, W2f, t2b, N);
    spmm_bf16_kernel<64, false><<<g64, 256, 0, stream>>>(t2b, row_ptr, cv, t3b, nullptr, N);
    spmm_bf16_kernel<64, true><<<g64, 256, 0, stream>>>(t3b, row_ptr, cv, out, b2, N);
}